// Round 2
// baseline (2948.412 us; speedup 1.0000x reference)
//
#include <hip/hip_runtime.h>
#include <hip/hip_bf16.h>
#include <math.h>

#define N_NODES 50000
#define F_IN    256
#define H       128
#define HEADS   4
#define HH      512   // HEADS*H
#define L_LAYERS 3
#define T_TYPES  3
#define E_EDGES  250000
#define NEG      0.2f

__device__ __forceinline__ float leaky(float x) { return x > 0.f ? x : NEG * x; }

__device__ __forceinline__ void fma4(float4& a, float s, float4 b) {
    a.x = fmaf(s, b.x, a.x); a.y = fmaf(s, b.y, a.y);
    a.z = fmaf(s, b.z, a.z); a.w = fmaf(s, b.w, a.w);
}

__device__ __forceinline__ unsigned short f2bf(float f) {
    union { float f; unsigned int i; } v; v.f = f;
    unsigned int x = v.i;
    unsigned int r = (x + 0x7fffu + ((x >> 16) & 1u)) >> 16;  // RNE
    return (unsigned short)r;
}

__device__ __forceinline__ void unpack8(uint4 q, float* o) {
    union { unsigned int i; float f; } v;
    v.i = q.x << 16;          o[0] = v.f;
    v.i = q.x & 0xffff0000u;  o[1] = v.f;
    v.i = q.y << 16;          o[2] = v.f;
    v.i = q.y & 0xffff0000u;  o[3] = v.f;
    v.i = q.z << 16;          o[4] = v.f;
    v.i = q.z & 0xffff0000u;  o[5] = v.f;
    v.i = q.w << 16;          o[6] = v.f;
    v.i = q.w & 0xffff0000u;  o[7] = v.f;
}

// ---------------- edge dtype detection: int64 vs int32 layout ----------------
// If the harness gives int64 (little-endian, ids < 2^31), every odd int32 word
// is 0. Genuine int32 edge data has random ids at odd words (all-zero prob ~0).
__global__ void detect_kernel(const int* __restrict__ edst, int* __restrict__ flag) {
    __shared__ int s_any;
    if (threadIdx.x == 0) s_any = 0;
    __syncthreads();
    int a = 0;
    #pragma unroll
    for (int j = 0; j < 8; ++j) a |= edst[2 * (threadIdx.x * 8 + j) + 1];
    if (a) atomicOr(&s_any, 1);
    __syncthreads();
    if (threadIdx.x == 0) *flag = s_any ? 0 : 1;  // 1 => int64 layout (stride 2)
}

// ---------------- CSR build ----------------
__global__ void hist_kernel(const int* __restrict__ edst, int* __restrict__ counts,
                            const int* __restrict__ flag) {
    int idx = blockIdx.x * 256 + threadIdx.x;
    if (idx < T_TYPES * E_EDGES) {
        int sh = *flag;
        int t = idx / E_EDGES;
        int d = edst[(size_t)idx << sh];
        if ((unsigned)d < N_NODES)
            atomicAdd(&counts[t * N_NODES + d], 1);
    }
}

// one block per edge type; counts[] is overwritten in place with cursor starts
__global__ void scan_kernel(int* __restrict__ counts, int* __restrict__ off) {
    __shared__ int sums[256];
    __shared__ int totsh;
    const int t = blockIdx.x, tid = threadIdx.x;
    int* cnt = counts + t * N_NODES;
    int* o   = off + t * (N_NODES + 1);
    const int CH = (N_NODES + 255) / 256;  // 196
    const int base = tid * CH;
    int s = 0;
    for (int j = 0; j < CH; ++j) { int i = base + j; if (i < N_NODES) s += cnt[i]; }
    sums[tid] = s;
    __syncthreads();
    if (tid == 0) {
        int run = 0;
        for (int i = 0; i < 256; ++i) { int v = sums[i]; sums[i] = run; run += v; }
        totsh = run;
    }
    __syncthreads();
    int run = sums[tid];
    for (int j = 0; j < CH; ++j) {
        int i = base + j;
        if (i < N_NODES) { int c = cnt[i]; o[i] = run; cnt[i] = run; run += c; }
    }
    if (tid == 0) o[N_NODES] = totsh;
}

__global__ void scatter_kernel(const int* __restrict__ esrc, const int* __restrict__ edst,
                               int* __restrict__ cursor, int* __restrict__ csrc,
                               const int* __restrict__ flag) {
    int idx = blockIdx.x * 256 + threadIdx.x;
    if (idx < T_TYPES * E_EDGES) {
        int sh = *flag;
        int t = idx / E_EDGES;
        int d = edst[(size_t)idx << sh];
        if ((unsigned)d >= N_NODES) return;
        int s = esrc[(size_t)idx << sh];
        if ((unsigned)s >= N_NODES) s = 0;
        int pos = atomicAdd(&cursor[t * N_NODES + d], 1);
        csrc[(size_t)t * E_EDGES + pos] = s;
    }
}

// ---------------- init: h = leaky(LN(feat@W+b)), x0 = 0.7h + 0.5*l2norm(emb) ----------------
// 8 nodes per 128-thread block
__global__ __launch_bounds__(128) void init_kernel(
    const float* __restrict__ feat, const float* __restrict__ emb,
    const float* __restrict__ W, const float* __restrict__ pb,
    const float* __restrict__ g, const float* __restrict__ b,
    float* __restrict__ x0, float* __restrict__ xcur)
{
    __shared__ float lds[8][F_IN];
    __shared__ float s0[2], s1[2];
    const int tid = threadIdx.x;
    const int nb = blockIdx.x * 8;
    #pragma unroll
    for (int it = 0; it < 4; ++it) {
        int f = it * 512 + tid * 4;
        int r = f >> 8, c = f & 255;
        int node = nb + r;
        float4 v = make_float4(0.f, 0.f, 0.f, 0.f);
        if (node < N_NODES) v = *(const float4*)(feat + (size_t)node * F_IN + c);
        *(float4*)&lds[r][c] = v;
    }
    __syncthreads();
    const int c = tid;  // output column 0..127
    float acc[8];
    #pragma unroll
    for (int nn = 0; nn < 8; ++nn) acc[nn] = 0.f;
    for (int k = 0; k < F_IN; k += 4) {
        float w0 = W[(k + 0) * H + c];
        float w1 = W[(k + 1) * H + c];
        float w2 = W[(k + 2) * H + c];
        float w3 = W[(k + 3) * H + c];
        #pragma unroll
        for (int nn = 0; nn < 8; ++nn) {
            float4 xv = *(const float4*)&lds[nn][k];
            acc[nn] = fmaf(xv.x, w0, fmaf(xv.y, w1, fmaf(xv.z, w2, fmaf(xv.w, w3, acc[nn]))));
        }
    }
    const float pbc = pb[c], gc = g[c], bc = b[c];
    for (int nn = 0; nn < 8; ++nn) {
        float v = acc[nn] + pbc;
        float sum = v, sq = v * v;
        for (int o = 32; o > 0; o >>= 1) { sum += __shfl_down(sum, o); sq += __shfl_down(sq, o); }
        if ((tid & 63) == 0) { s0[tid >> 6] = sum; s1[tid >> 6] = sq; }
        __syncthreads();
        float tot = s0[0] + s0[1], tq = s1[0] + s1[1];
        __syncthreads();
        float mu = tot * (1.f / H);
        float var = tq * (1.f / H) - mu * mu;
        acc[nn] = leaky((v - mu) * rsqrtf(var + 1e-5f) * gc + bc);
    }
    for (int nn = 0; nn < 8; ++nn) {
        int node = nb + nn;
        float ev = (node < N_NODES) ? emb[(size_t)node * H + c] : 0.f;
        float sq = ev * ev;
        for (int o = 32; o > 0; o >>= 1) sq += __shfl_down(sq, o);
        if ((tid & 63) == 0) s0[tid >> 6] = sq;
        __syncthreads();
        float nrm = sqrtf(s0[0] + s0[1]);
        __syncthreads();
        float nev = ev / fmaxf(nrm, 1e-12f);
        float xv = 0.7f * acc[nn] + 0.5f * nev;
        if (node < N_NODES) {
            x0[(size_t)node * H + c] = xv;
            xcur[(size_t)node * H + c] = xv;
        }
    }
}

// ---------------- XL/XR GEMM: [N,128] @ [128,512] x2 -> bf16, 64x64 tile, 4x4/thread -------
__global__ __launch_bounds__(256) void gemm_xlr_kernel(
    const float* __restrict__ x,
    const float* __restrict__ Wl, const float* __restrict__ Wr,
    unsigned short* __restrict__ XL, unsigned short* __restrict__ XR)
{
    __shared__ float xs[64][132];  // +4 pad keeps float4 alignment, staggers banks
    const int tid = threadIdx.x;
    const int nb = blockIdx.x * 64;
    #pragma unroll
    for (int it = 0; it < 8; ++it) {
        int f = it * 1024 + tid * 4;
        int r = f >> 7, c = f & 127;
        int node = nb + r;
        float4 v = make_float4(0.f, 0.f, 0.f, 0.f);
        if (node < N_NODES) v = *(const float4*)(x + (size_t)node * H + c);
        *(float4*)&xs[r][c] = v;
    }
    __syncthreads();
    const int cg = tid & 15, ng = tid >> 4;
    const int c0 = blockIdx.y * 64 + cg * 4;  // 0..1023
    const float* B; unsigned short* O; int oc;
    if (c0 < HH) { B = Wl; O = XL; oc = c0; }
    else         { B = Wr; O = XR; oc = c0 - HH; }
    const int r0 = ng * 4;
    float4 acc[4];
    acc[0] = acc[1] = acc[2] = acc[3] = make_float4(0.f, 0.f, 0.f, 0.f);
    for (int k = 0; k < H; k += 4) {
        float4 b0 = *(const float4*)(B + (size_t)(k + 0) * HH + oc);
        float4 b1 = *(const float4*)(B + (size_t)(k + 1) * HH + oc);
        float4 b2 = *(const float4*)(B + (size_t)(k + 2) * HH + oc);
        float4 b3 = *(const float4*)(B + (size_t)(k + 3) * HH + oc);
        #pragma unroll
        for (int nn = 0; nn < 4; ++nn) {
            float4 xv = *(const float4*)&xs[r0 + nn][k];
            fma4(acc[nn], xv.x, b0);
            fma4(acc[nn], xv.y, b1);
            fma4(acc[nn], xv.z, b2);
            fma4(acc[nn], xv.w, b3);
        }
    }
    #pragma unroll
    for (int nn = 0; nn < 4; ++nn) {
        int node = nb + r0 + nn;
        if (node < N_NODES) {
            ushort4 o;
            o.x = f2bf(acc[nn].x); o.y = f2bf(acc[nn].y);
            o.z = f2bf(acc[nn].z); o.w = f2bf(acc[nn].w);
            *(ushort4*)(O + (size_t)node * HH + oc) = o;
        }
    }
}

// ---------------- per-dst flash-style GATv2 aggregation: 1 wave = 1 dst node ----------------
__global__ __launch_bounds__(256) void aggregate_kernel(
    const unsigned short* __restrict__ XL, const unsigned short* __restrict__ XR,
    const float* __restrict__ att_t, const float* __restrict__ bias_t,
    const int* __restrict__ off, const int* __restrict__ csrc,
    float* __restrict__ xacc, int first)
{
    const int tid = threadIdx.x;
    const int lane = tid & 63;
    const int wid = tid >> 6;
    const int d = blockIdx.x * 4 + wid;
    if (d >= N_NODES) return;
    const int jb = lane * 8;  // flat index into [HEADS*H]; head = lane/16

    float rv[8], av[8], acc[8];
    {
        uint4 q = *(const uint4*)(XR + (size_t)d * HH + jb);
        unpack8(q, rv);
        float4 u0 = *(const float4*)(att_t + jb);
        float4 u1 = *(const float4*)(att_t + jb + 4);
        av[0] = u0.x; av[1] = u0.y; av[2] = u0.z; av[3] = u0.w;
        av[4] = u1.x; av[5] = u1.y; av[6] = u1.z; av[7] = u1.w;
    }
    #pragma unroll
    for (int u = 0; u < 8; ++u) acc[u] = 0.f;
    float den = 0.f, rmax = -INFINITY;

    const int e1 = off[d + 1];
    for (int e = off[d]; e < e1; ++e) {
        int s = csrc[e];
        if ((unsigned)s >= N_NODES) s = 0;  // defensive: poison -> wrong number, not fault
        uint4 q = *(const uint4*)(XL + (size_t)s * HH + jb);
        float lv[8];
        unpack8(q, lv);
        float p = 0.f;
        #pragma unroll
        for (int u = 0; u < 8; ++u) {
            float m = lv[u] + rv[u];
            p = fmaf(av[u], leaky(m), p);
        }
        // reduce over the 16 lanes of this head
        p += __shfl_xor(p, 1);
        p += __shfl_xor(p, 2);
        p += __shfl_xor(p, 4);
        p += __shfl_xor(p, 8);
        float nm = fmaxf(rmax, p);
        float sc = __expf(rmax - nm);  // first iter: exp(-inf)=0
        float w  = __expf(p - nm);
        den = den * sc + w;
        #pragma unroll
        for (int u = 0; u < 8; ++u) acc[u] = fmaf(acc[u], sc, w * lv[u]);
        rmax = nm;
    }
    float inv = 1.f / (den + 1e-16f);
    #pragma unroll
    for (int u = 0; u < 8; ++u) {
        float v = acc[u] * inv;
        v += __shfl_xor(v, 16);   // sum across 4 heads (same H-col)
        v += __shfl_xor(v, 32);
        acc[u] = v * 0.25f;
    }
    if (lane < 16) {              // lanes 0..15 hold the 128 head-mean values
        float* dst = xacc + (size_t)d * H + jb;
        float o[8];
        #pragma unroll
        for (int u = 0; u < 8; ++u) o[u] = acc[u] + bias_t[jb + u];
        float4 o0 = make_float4(o[0], o[1], o[2], o[3]);
        float4 o1 = make_float4(o[4], o[5], o[6], o[7]);
        if (first) {
            *(float4*)dst = o0;
            *(float4*)(dst + 4) = o1;
        } else {
            float4 c0 = *(const float4*)dst, c1 = *(const float4*)(dst + 4);
            o0.x += c0.x; o0.y += c0.y; o0.z += c0.z; o0.w += c0.w;
            o1.x += c1.x; o1.y += c1.y; o1.z += c1.z; o1.w += c1.w;
            *(float4*)dst = o0;
            *(float4*)(dst + 4) = o1;
        }
    }
}

// ---------------- layer epilogue: x = leaky(xacc/3) + sigmoid(skip_w[i]) * x0 ----------------
// NOTE: xacc may alias out (xacc lives in d_out) -> no __restrict__ on those two.
__global__ __launch_bounds__(256) void epilogue_kernel(
    const float* xacc, const float* __restrict__ x0,
    const float* __restrict__ skipw, int li, float* out)
{
    size_t i = ((size_t)blockIdx.x * 256 + threadIdx.x) * 4;
    float sw = 1.f / (1.f + __expf(-skipw[li]));
    float4 a = *(const float4*)(xacc + i);
    float4 z = *(const float4*)(x0 + i);
    float4 o;
    o.x = leaky(a.x * (1.f / 3.f)) + sw * z.x;
    o.y = leaky(a.y * (1.f / 3.f)) + sw * z.y;
    o.z = leaky(a.z * (1.f / 3.f)) + sw * z.z;
    o.w = leaky(a.w * (1.f / 3.f)) + sw * z.w;
    *(float4*)(out + i) = o;
}

extern "C" void kernel_launch(void* const* d_in, const int* in_sizes, int n_in,
                              void* d_out, int out_size, void* d_ws, size_t ws_size,
                              hipStream_t stream)
{
    const float* feat   = (const float*)d_in[0];
    const float* emb    = (const float*)d_in[1];
    const float* proj_w = (const float*)d_in[2];
    const float* proj_b = (const float*)d_in[3];
    const float* ln_g   = (const float*)d_in[4];
    const float* ln_b   = (const float*)d_in[5];
    const float* skip_w = (const float*)d_in[6];
    const float* Wl     = (const float*)d_in[7];
    const float* Wr     = (const float*)d_in[8];
    const float* att    = (const float*)d_in[9];
    const float* bias   = (const float*)d_in[10];
    const int*   esrc   = (const int*)d_in[11];
    const int*   edst   = (const int*)d_in[12];
    float* out = (float*)d_out;

    char* p = (char*)d_ws;
    auto alloc = [&](size_t bytes) -> char* {
        char* r = p; p += (bytes + 255) & ~(size_t)255; return r;
    };
    // ws footprint: 25.6 + 25.6 + 51.2 + 51.2 + ~4.3 MB ~= 158 MB
    float* x0            = (float*)alloc((size_t)N_NODES * H * 4);
    float* xcur          = (float*)alloc((size_t)N_NODES * H * 4);
    unsigned short* XL   = (unsigned short*)alloc((size_t)N_NODES * HH * 2);
    unsigned short* XR   = (unsigned short*)alloc((size_t)N_NODES * HH * 2);
    int* off    = (int*)alloc((size_t)T_TYPES * (N_NODES + 1) * 4);
    int* cursor = (int*)alloc((size_t)T_TYPES * N_NODES * 4);
    int* csrc   = (int*)alloc((size_t)T_TYPES * E_EDGES * 4);
    int* eflag  = (int*)alloc(256);
    float* xacc = out;  // alias scratch accumulator onto d_out (saves 25.6 MB)

    // CSR by dst (edge lists are layer-invariant; built once per call)
    detect_kernel<<<1, 256, 0, stream>>>(edst, eflag);
    hipMemsetAsync(cursor, 0, (size_t)T_TYPES * N_NODES * 4, stream);
    hist_kernel<<<(T_TYPES * E_EDGES + 255) / 256, 256, 0, stream>>>(edst, cursor, eflag);
    scan_kernel<<<T_TYPES, 256, 0, stream>>>(cursor, off);
    scatter_kernel<<<(T_TYPES * E_EDGES + 255) / 256, 256, 0, stream>>>(esrc, edst, cursor, csrc, eflag);

    init_kernel<<<N_NODES / 8, 128, 0, stream>>>(feat, emb, proj_w, proj_b, ln_g, ln_b, x0, xcur);

    for (int i = 0; i < L_LAYERS; ++i) {
        for (int t = 0; t < T_TYPES; ++t) {
            const float* wl = Wl + (size_t)(i * T_TYPES + t) * H * HH;
            const float* wr = Wr + (size_t)(i * T_TYPES + t) * H * HH;
            const float* at = att + (size_t)(i * T_TYPES + t) * HEADS * H;
            const float* bi = bias + (size_t)(i * T_TYPES + t) * H;
            gemm_xlr_kernel<<<dim3((N_NODES + 63) / 64, 16), 256, 0, stream>>>(xcur, wl, wr, XL, XR);
            aggregate_kernel<<<(N_NODES + 3) / 4, 256, 0, stream>>>(
                XL, XR, at, bi, off + t * (N_NODES + 1), csrc + (size_t)t * E_EDGES,
                xacc, (t == 0) ? 1 : 0);
        }
        epilogue_kernel<<<(N_NODES * H / 4) / 256, 256, 0, stream>>>(
            xacc, x0, skip_w, i, (i == L_LAYERS - 1) ? out : xcur);
    }
}

// Round 3
// 1397.884 us; speedup vs baseline: 2.1092x; 2.1092x over previous
//
#include <hip/hip_runtime.h>
#include <hip/hip_bf16.h>
#include <math.h>

#define N_NODES 50000
#define F_IN    256
#define H       128
#define HEADS   4
#define HH      512   // HEADS*H
#define L_LAYERS 3
#define T_TYPES  3
#define E_EDGES  250000
#define NEG      0.2f

typedef __attribute__((ext_vector_type(8))) short short8_t;   // 8 bf16 (4 VGPRs)
typedef __attribute__((ext_vector_type(4))) float float4_t;

__device__ __forceinline__ float leaky(float x) { return x > 0.f ? x : NEG * x; }

__device__ __forceinline__ unsigned short f2bf(float f) {
    union { float f; unsigned int i; } v; v.f = f;
    unsigned int x = v.i;
    unsigned int r = (x + 0x7fffu + ((x >> 16) & 1u)) >> 16;  // RNE
    return (unsigned short)r;
}

__device__ __forceinline__ void unpack8(uint4 q, float* o) {
    union { unsigned int i; float f; } v;
    v.i = q.x << 16;          o[0] = v.f;
    v.i = q.x & 0xffff0000u;  o[1] = v.f;
    v.i = q.y << 16;          o[2] = v.f;
    v.i = q.y & 0xffff0000u;  o[3] = v.f;
    v.i = q.z << 16;          o[4] = v.f;
    v.i = q.z & 0xffff0000u;  o[5] = v.f;
    v.i = q.w << 16;          o[6] = v.f;
    v.i = q.w & 0xffff0000u;  o[7] = v.f;
}

// ---------------- edge dtype detection: int64 vs int32 layout ----------------
__global__ void detect_kernel(const int* __restrict__ edst, int* __restrict__ flag) {
    __shared__ int s_any;
    if (threadIdx.x == 0) s_any = 0;
    __syncthreads();
    int a = 0;
    #pragma unroll
    for (int j = 0; j < 8; ++j) a |= edst[2 * (threadIdx.x * 8 + j) + 1];
    if (a) atomicOr(&s_any, 1);
    __syncthreads();
    if (threadIdx.x == 0) *flag = s_any ? 0 : 1;  // 1 => int64 layout (stride 2)
}

// ---------------- CSR build ----------------
__global__ void hist_kernel(const int* __restrict__ edst, int* __restrict__ counts,
                            const int* __restrict__ flag) {
    int idx = blockIdx.x * 256 + threadIdx.x;
    if (idx < T_TYPES * E_EDGES) {
        int sh = *flag;
        int t = idx / E_EDGES;
        int d = edst[(size_t)idx << sh];
        if ((unsigned)d < N_NODES)
            atomicAdd(&counts[t * N_NODES + d], 1);
    }
}

__global__ void scan_kernel(int* __restrict__ counts, int* __restrict__ off) {
    __shared__ int sums[256];
    __shared__ int totsh;
    const int t = blockIdx.x, tid = threadIdx.x;
    int* cnt = counts + t * N_NODES;
    int* o   = off + t * (N_NODES + 1);
    const int CH = (N_NODES + 255) / 256;  // 196
    const int base = tid * CH;
    int s = 0;
    for (int j = 0; j < CH; ++j) { int i = base + j; if (i < N_NODES) s += cnt[i]; }
    sums[tid] = s;
    __syncthreads();
    if (tid == 0) {
        int run = 0;
        for (int i = 0; i < 256; ++i) { int v = sums[i]; sums[i] = run; run += v; }
        totsh = run;
    }
    __syncthreads();
    int run = sums[tid];
    for (int j = 0; j < CH; ++j) {
        int i = base + j;
        if (i < N_NODES) { int c = cnt[i]; o[i] = run; cnt[i] = run; run += c; }
    }
    if (tid == 0) o[N_NODES] = totsh;
}

__global__ void scatter_kernel(const int* __restrict__ esrc, const int* __restrict__ edst,
                               int* __restrict__ cursor, int* __restrict__ csrc,
                               const int* __restrict__ flag) {
    int idx = blockIdx.x * 256 + threadIdx.x;
    if (idx < T_TYPES * E_EDGES) {
        int sh = *flag;
        int t = idx / E_EDGES;
        int d = edst[(size_t)idx << sh];
        if ((unsigned)d >= N_NODES) return;
        int s = esrc[(size_t)idx << sh];
        if ((unsigned)s >= N_NODES) s = 0;
        int pos = atomicAdd(&cursor[t * N_NODES + d], 1);
        csrc[(size_t)t * E_EDGES + pos] = s;
    }
}

// ---------------- weight convert: Wt[lt][c(0..1023)][k] = bf16(W{l,r}[lt][k][c]) -----------
__global__ void wconv_kernel(const float* __restrict__ Wl, const float* __restrict__ Wr,
                             unsigned short* __restrict__ Wt) {
    int idx = blockIdx.x * 256 + threadIdx.x;   // output-ordered: coalesced writes
    if (idx >= L_LAYERS * T_TYPES * 1024 * H) return;
    int lt  = idx / (1024 * H);
    int rem = idx - lt * (1024 * H);
    int c   = rem / H;
    int k   = rem - c * H;
    float v = (c < HH) ? Wl[(size_t)lt * H * HH + (size_t)k * HH + c]
                       : Wr[(size_t)lt * H * HH + (size_t)k * HH + (c - HH)];
    Wt[idx] = f2bf(v);
}

// ---------------- init: h = leaky(LN(feat@W+b)), x0 = 0.7h + 0.5*l2norm(emb) ----------------
__global__ __launch_bounds__(128) void init_kernel(
    const float* __restrict__ feat, const float* __restrict__ emb,
    const float* __restrict__ W, const float* __restrict__ pb,
    const float* __restrict__ g, const float* __restrict__ b,
    float* __restrict__ x0, unsigned short* __restrict__ xcurb)
{
    __shared__ float lds[8][F_IN];
    __shared__ float s0[2], s1[2];
    const int tid = threadIdx.x;
    const int nb = blockIdx.x * 8;
    #pragma unroll
    for (int it = 0; it < 4; ++it) {
        int f = it * 512 + tid * 4;
        int r = f >> 8, c = f & 255;
        int node = nb + r;
        float4 v = make_float4(0.f, 0.f, 0.f, 0.f);
        if (node < N_NODES) v = *(const float4*)(feat + (size_t)node * F_IN + c);
        *(float4*)&lds[r][c] = v;
    }
    __syncthreads();
    const int c = tid;
    float acc[8];
    #pragma unroll
    for (int nn = 0; nn < 8; ++nn) acc[nn] = 0.f;
    for (int k = 0; k < F_IN; k += 4) {
        float w0 = W[(k + 0) * H + c];
        float w1 = W[(k + 1) * H + c];
        float w2 = W[(k + 2) * H + c];
        float w3 = W[(k + 3) * H + c];
        #pragma unroll
        for (int nn = 0; nn < 8; ++nn) {
            float4 xv = *(const float4*)&lds[nn][k];
            acc[nn] = fmaf(xv.x, w0, fmaf(xv.y, w1, fmaf(xv.z, w2, fmaf(xv.w, w3, acc[nn]))));
        }
    }
    const float pbc = pb[c], gc = g[c], bc = b[c];
    for (int nn = 0; nn < 8; ++nn) {
        float v = acc[nn] + pbc;
        float sum = v, sq = v * v;
        for (int o = 32; o > 0; o >>= 1) { sum += __shfl_down(sum, o); sq += __shfl_down(sq, o); }
        if ((tid & 63) == 0) { s0[tid >> 6] = sum; s1[tid >> 6] = sq; }
        __syncthreads();
        float tot = s0[0] + s0[1], tq = s1[0] + s1[1];
        __syncthreads();
        float mu = tot * (1.f / H);
        float var = tq * (1.f / H) - mu * mu;
        acc[nn] = leaky((v - mu) * rsqrtf(var + 1e-5f) * gc + bc);
    }
    for (int nn = 0; nn < 8; ++nn) {
        int node = nb + nn;
        float ev = (node < N_NODES) ? emb[(size_t)node * H + c] : 0.f;
        float sq = ev * ev;
        for (int o = 32; o > 0; o >>= 1) sq += __shfl_down(sq, o);
        if ((tid & 63) == 0) s0[tid >> 6] = sq;
        __syncthreads();
        float nrm = sqrtf(s0[0] + s0[1]);
        __syncthreads();
        float nev = ev / fmaxf(nrm, 1e-12f);
        float xv = 0.7f * acc[nn] + 0.5f * nev;
        if (node < N_NODES) {
            x0[(size_t)node * H + c] = xv;
            xcurb[(size_t)node * H + c] = f2bf(xv);
        }
    }
}

// ---------------- MFMA GEMM: [N,128]bf16 @ Wt^T -> XL|XR bf16, 128x128 tile ----------------
// 4 waves in 2x2; per wave 4x4 tiles of mfma_f32_16x16x32_bf16; K=128 fully LDS-resident.
// A/B tiles XOR-swizzled at 16B-chunk granularity (conflict-free frag reads, no padding).
// C round-trips through LDS (overlaying A/B) for coalesced 16B global stores.
__global__ __launch_bounds__(256) void gemm_mfma_kernel(
    const unsigned short* __restrict__ x,    // [N][128] bf16
    const unsigned short* __restrict__ Wt,   // [1024][128] bf16 (this layer-type)
    unsigned short* __restrict__ XL, unsigned short* __restrict__ XR)
{
    __shared__ unsigned short smem[32768];   // 64 KB: As 32K | Bs 32K, then C overlay
    unsigned short* As = smem;               // [128][128] swizzled
    unsigned short* Bs = smem + 16384;       // [128][128] swizzled
    const int tid = threadIdx.x;
    const int nb = blockIdx.x * 128;
    const int cb = blockIdx.y * 128;

    // stage A (x rows) and B (Wt rows = output cols): 2048 16B-chunks each half
    #pragma unroll
    for (int it = 0; it < 8; ++it) {
        int c = it * 256 + tid;
        int r = c >> 4;                       // 0..127
        int k8 = c & 15;                      // 16B chunk index within row
        int slot = (k8 ^ (r & 15)) * 8;       // XOR swizzle
        int node = nb + r;
        uint4 va = make_uint4(0, 0, 0, 0);
        if (node < N_NODES) va = *(const uint4*)(x + (size_t)node * H + k8 * 8);
        *(uint4*)(As + r * H + slot) = va;
        uint4 vb = *(const uint4*)(Wt + (size_t)(cb + r) * H + k8 * 8);
        *(uint4*)(Bs + r * H + slot) = vb;
    }
    __syncthreads();

    const int wv = tid >> 6, lane = tid & 63;
    const int lm = lane & 15, kg = lane >> 4;
    const int wm = (wv & 1) * 64, wn = (wv >> 1) * 64;
    float4_t acc[4][4];
    #pragma unroll
    for (int i = 0; i < 4; ++i)
        #pragma unroll
        for (int j = 0; j < 4; ++j)
            acc[i][j] = (float4_t){0.f, 0.f, 0.f, 0.f};

    #pragma unroll
    for (int ks = 0; ks < 4; ++ks) {
        const int K8 = ks * 4 + kg;           // logical 16B chunk along K
        const int slot = (K8 ^ lm) * 8;       // same swizzle (row%16 == lm)
        short8_t a[4], b[4];
        #pragma unroll
        for (int i = 0; i < 4; ++i) {
            a[i] = *(const short8_t*)(As + (wm + i * 16 + lm) * H + slot);
            b[i] = *(const short8_t*)(Bs + (wn + i * 16 + lm) * H + slot);
        }
        #pragma unroll
        for (int i = 0; i < 4; ++i)
            #pragma unroll
            for (int j = 0; j < 4; ++j)
                acc[i][j] = __builtin_amdgcn_mfma_f32_16x16x32_bf16(a[i], b[j], acc[i][j], 0, 0, 0);
    }
    __syncthreads();

    // C -> LDS overlay [128][136] (pad keeps uint4-aligned rows), then coalesced stores
    unsigned short* Cs = smem;
    #pragma unroll
    for (int i = 0; i < 4; ++i) {
        int row0 = wm + i * 16 + kg * 4;      // C/D: col=lane&15, row=kg*4+reg
        #pragma unroll
        for (int j = 0; j < 4; ++j) {
            int col = wn + j * 16 + lm;
            #pragma unroll
            for (int r = 0; r < 4; ++r)
                Cs[(row0 + r) * 136 + col] = f2bf(acc[i][j][r]);
        }
    }
    __syncthreads();

    unsigned short* O = (blockIdx.y < 4) ? XL : XR;
    const int cbase = (blockIdx.y < 4) ? cb : cb - HH;
    #pragma unroll
    for (int it = 0; it < 8; ++it) {
        int c = it * 256 + tid;
        int r = c >> 4, k8 = (c & 15) * 8;
        int node = nb + r;
        if (node < N_NODES)
            *(uint4*)(O + (size_t)node * HH + cbase + k8) = *(const uint4*)(Cs + r * 136 + k8);
    }
}

// ---------------- per-dst flash-style GATv2 aggregation: 1 wave = 1 dst node ----------------
__global__ __launch_bounds__(256) void aggregate_kernel(
    const unsigned short* __restrict__ XL, const unsigned short* __restrict__ XR,
    const float* __restrict__ att_t, const float* __restrict__ bias_t,
    const int* __restrict__ off, const int* __restrict__ csrc,
    float* __restrict__ xacc, int first)
{
    const int tid = threadIdx.x;
    const int lane = tid & 63;
    const int wid = tid >> 6;
    const int d = blockIdx.x * 4 + wid;
    if (d >= N_NODES) return;
    const int jb = lane * 8;

    float rv[8], av[8], acc[8];
    {
        uint4 q = *(const uint4*)(XR + (size_t)d * HH + jb);
        unpack8(q, rv);
        float4 u0 = *(const float4*)(att_t + jb);
        float4 u1 = *(const float4*)(att_t + jb + 4);
        av[0] = u0.x; av[1] = u0.y; av[2] = u0.z; av[3] = u0.w;
        av[4] = u1.x; av[5] = u1.y; av[6] = u1.z; av[7] = u1.w;
    }
    #pragma unroll
    for (int u = 0; u < 8; ++u) acc[u] = 0.f;
    float den = 0.f, rmax = -INFINITY;

    const int e1 = off[d + 1];
    for (int e = off[d]; e < e1; ++e) {
        int s = csrc[e];
        if ((unsigned)s >= N_NODES) s = 0;
        uint4 q = *(const uint4*)(XL + (size_t)s * HH + jb);
        float lv[8];
        unpack8(q, lv);
        float p = 0.f;
        #pragma unroll
        for (int u = 0; u < 8; ++u) {
            float m = lv[u] + rv[u];
            p = fmaf(av[u], leaky(m), p);
        }
        p += __shfl_xor(p, 1);
        p += __shfl_xor(p, 2);
        p += __shfl_xor(p, 4);
        p += __shfl_xor(p, 8);
        float nm = fmaxf(rmax, p);
        float sc = __expf(rmax - nm);
        float w  = __expf(p - nm);
        den = den * sc + w;
        #pragma unroll
        for (int u = 0; u < 8; ++u) acc[u] = fmaf(acc[u], sc, w * lv[u]);
        rmax = nm;
    }
    float inv = 1.f / (den + 1e-16f);
    #pragma unroll
    for (int u = 0; u < 8; ++u) {
        float v = acc[u] * inv;
        v += __shfl_xor(v, 16);
        v += __shfl_xor(v, 32);
        acc[u] = v * 0.25f;
    }
    if (lane < 16) {
        float* dst = xacc + (size_t)d * H + jb;
        float o[8];
        #pragma unroll
        for (int u = 0; u < 8; ++u) o[u] = acc[u] + bias_t[jb + u];
        float4 o0 = make_float4(o[0], o[1], o[2], o[3]);
        float4 o1 = make_float4(o[4], o[5], o[6], o[7]);
        if (first) {
            *(float4*)dst = o0;
            *(float4*)(dst + 4) = o1;
        } else {
            float4 c0 = *(const float4*)dst, c1 = *(const float4*)(dst + 4);
            o0.x += c0.x; o0.y += c0.y; o0.z += c0.z; o0.w += c0.w;
            o1.x += c1.x; o1.y += c1.y; o1.z += c1.z; o1.w += c1.w;
            *(float4*)dst = o0;
            *(float4*)(dst + 4) = o1;
        }
    }
}

// ---------------- layer epilogue ----------------
// xacc aliases out; writes bf16 xcurb (non-last) or fp32 out (last).
__global__ __launch_bounds__(256) void epilogue_kernel(
    const float* xacc, const float* __restrict__ x0,
    const float* __restrict__ skipw, int li, int last,
    unsigned short* __restrict__ xcurb, float* out)
{
    size_t i = ((size_t)blockIdx.x * 256 + threadIdx.x) * 4;
    float sw = 1.f / (1.f + __expf(-skipw[li]));
    float4 a = *(const float4*)(xacc + i);
    float4 z = *(const float4*)(x0 + i);
    float o0 = leaky(a.x * (1.f / 3.f)) + sw * z.x;
    float o1 = leaky(a.y * (1.f / 3.f)) + sw * z.y;
    float o2 = leaky(a.z * (1.f / 3.f)) + sw * z.z;
    float o3 = leaky(a.w * (1.f / 3.f)) + sw * z.w;
    if (last) {
        *(float4*)(out + i) = make_float4(o0, o1, o2, o3);
    } else {
        ushort4 o;
        o.x = f2bf(o0); o.y = f2bf(o1); o.z = f2bf(o2); o.w = f2bf(o3);
        *(ushort4*)(xcurb + i) = o;
    }
}

extern "C" void kernel_launch(void* const* d_in, const int* in_sizes, int n_in,
                              void* d_out, int out_size, void* d_ws, size_t ws_size,
                              hipStream_t stream)
{
    const float* feat   = (const float*)d_in[0];
    const float* emb    = (const float*)d_in[1];
    const float* proj_w = (const float*)d_in[2];
    const float* proj_b = (const float*)d_in[3];
    const float* ln_g   = (const float*)d_in[4];
    const float* ln_b   = (const float*)d_in[5];
    const float* skip_w = (const float*)d_in[6];
    const float* Wl     = (const float*)d_in[7];
    const float* Wr     = (const float*)d_in[8];
    const float* att    = (const float*)d_in[9];
    const float* bias   = (const float*)d_in[10];
    const int*   esrc   = (const int*)d_in[11];
    const int*   edst   = (const int*)d_in[12];
    float* out = (float*)d_out;

    char* p = (char*)d_ws;
    auto alloc = [&](size_t bytes) -> char* {
        char* r = p; p += (bytes + 255) & ~(size_t)255; return r;
    };
    // ws: 25.6 + 12.8 + 51.2 + 51.2 + 2.4 + ~4.3 MB ~= 148 MB
    float* x0             = (float*)alloc((size_t)N_NODES * H * 4);
    unsigned short* xcurb = (unsigned short*)alloc((size_t)N_NODES * H * 2);
    unsigned short* XL    = (unsigned short*)alloc((size_t)N_NODES * HH * 2);
    unsigned short* XR    = (unsigned short*)alloc((size_t)N_NODES * HH * 2);
    unsigned short* Wt    = (unsigned short*)alloc((size_t)L_LAYERS * T_TYPES * 1024 * H * 2);
    int* off    = (int*)alloc((size_t)T_TYPES * (N_NODES + 1) * 4);
    int* cursor = (int*)alloc((size_t)T_TYPES * N_NODES * 4);
    int* csrc   = (int*)alloc((size_t)T_TYPES * E_EDGES * 4);
    int* eflag  = (int*)alloc(256);
    float* xacc = out;  // alias scratch accumulator onto d_out

    detect_kernel<<<1, 256, 0, stream>>>(edst, eflag);
    hipMemsetAsync(cursor, 0, (size_t)T_TYPES * N_NODES * 4, stream);
    hist_kernel<<<(T_TYPES * E_EDGES + 255) / 256, 256, 0, stream>>>(edst, cursor, eflag);
    scan_kernel<<<T_TYPES, 256, 0, stream>>>(cursor, off);
    scatter_kernel<<<(T_TYPES * E_EDGES + 255) / 256, 256, 0, stream>>>(esrc, edst, cursor, csrc, eflag);

    wconv_kernel<<<(L_LAYERS * T_TYPES * 1024 * H + 255) / 256, 256, 0, stream>>>(Wl, Wr, Wt);
    init_kernel<<<N_NODES / 8, 128, 0, stream>>>(feat, emb, proj_w, proj_b, ln_g, ln_b, x0, xcurb);

    for (int i = 0; i < L_LAYERS; ++i) {
        for (int t = 0; t < T_TYPES; ++t) {
            const int lt = i * T_TYPES + t;
            const unsigned short* wt = Wt + (size_t)lt * 1024 * H;
            const float* at = att + (size_t)lt * HEADS * H;
            const float* bi = bias + (size_t)lt * H;
            gemm_mfma_kernel<<<dim3((N_NODES + 127) / 128, 8), 256, 0, stream>>>(xcurb, wt, XL, XR);
            aggregate_kernel<<<(N_NODES + 3) / 4, 256, 0, stream>>>(
                XL, XR, at, bi, off + t * (N_NODES + 1), csrc + (size_t)t * E_EDGES,
                xacc, (t == 0) ? 1 : 0);
        }
        epilogue_kernel<<<(N_NODES * H / 4) / 256, 256, 0, stream>>>(
            xacc, x0, skip_w, i, (i == L_LAYERS - 1) ? 1 : 0, xcurb, out);
    }
}

// Round 6
// 1226.744 us; speedup vs baseline: 2.4034x; 1.1395x over previous
//
#include <hip/hip_runtime.h>
#include <hip/hip_bf16.h>
#include <math.h>

#define N_NODES 50000
#define NOFF    50004   // padded off-array stride (16B-aligned int4 stores)
#define NBLK    49      // ceil(N_NODES/1024) scan blocks per type
#define F_IN    256
#define H       128
#define HEADS   4
#define HH      512   // HEADS*H
#define L_LAYERS 3
#define T_TYPES  3
#define E_EDGES  250000
#define NEG      0.2f

typedef __attribute__((ext_vector_type(8))) short short8_t;   // 8 bf16 (4 VGPRs)
typedef __attribute__((ext_vector_type(4))) float float4_t;

__device__ __forceinline__ float leaky(float x) { return x > 0.f ? x : NEG * x; }

__device__ __forceinline__ unsigned short f2bf(float f) {
    union { float f; unsigned int i; } v; v.f = f;
    unsigned int x = v.i;
    unsigned int r = (x + 0x7fffu + ((x >> 16) & 1u)) >> 16;  // RNE
    return (unsigned short)r;
}

__device__ __forceinline__ void unpack8(uint4 q, float* o) {
    union { unsigned int i; float f; } v;
    v.i = q.x << 16;          o[0] = v.f;
    v.i = q.x & 0xffff0000u;  o[1] = v.f;
    v.i = q.y << 16;          o[2] = v.f;
    v.i = q.y & 0xffff0000u;  o[3] = v.f;
    v.i = q.z << 16;          o[4] = v.f;
    v.i = q.z & 0xffff0000u;  o[5] = v.f;
    v.i = q.w << 16;          o[6] = v.f;
    v.i = q.w & 0xffff0000u;  o[7] = v.f;
}

// ---------------- edge dtype detection: int64 vs int32 layout ----------------
__global__ void detect_kernel(const int* __restrict__ edst, int* __restrict__ flag) {
    __shared__ int s_any;
    if (threadIdx.x == 0) s_any = 0;
    __syncthreads();
    int a = 0;
    #pragma unroll
    for (int j = 0; j < 8; ++j) a |= edst[2 * (threadIdx.x * 8 + j) + 1];
    if (a) atomicOr(&s_any, 1);
    __syncthreads();
    if (threadIdx.x == 0) *flag = s_any ? 0 : 1;  // 1 => int64 layout (stride 2)
}

// ---------------- CSR build ----------------
__global__ void hist_kernel(const int* __restrict__ edst, int* __restrict__ counts,
                            const int* __restrict__ flag) {
    int idx = blockIdx.x * 256 + threadIdx.x;
    if (idx < T_TYPES * E_EDGES) {
        int sh = *flag;
        int t = idx / E_EDGES;
        int d = edst[(size_t)idx << sh];
        if ((unsigned)d < N_NODES)
            atomicAdd(&counts[t * N_NODES + d], 1);
    }
}

// Phase A: per-block partial sums (1024 counts/block, int4-coalesced)
__global__ __launch_bounds__(256) void scan_a_kernel(const int* __restrict__ counts,
                                                     int* __restrict__ bsum) {
    const int b = blockIdx.x;
    const int t = b / NBLK, ch = b % NBLK;
    const int tid = threadIdx.x, lane = tid & 63;
    __shared__ int ws[4];
    const int* cnt = counts + t * N_NODES;
    int i0 = ch * 1024 + tid * 4;
    int s = 0;
    if (i0 + 3 < N_NODES) { int4 v = *(const int4*)(cnt + i0); s = v.x + v.y + v.z + v.w; }
    else { for (int j = 0; j < 4; ++j) { int i = i0 + j; if (i < N_NODES) s += cnt[i]; } }
    #pragma unroll
    for (int o = 32; o > 0; o >>= 1) s += __shfl_xor(s, o);
    if (lane == 0) ws[tid >> 6] = s;
    __syncthreads();
    if (tid == 0) bsum[b] = ws[0] + ws[1] + ws[2] + ws[3];
}

// Phase B: exclusive-scan the 49 block sums per type (tiny, 1 block)
__global__ void scan_b_kernel(int* __restrict__ bsum, int* __restrict__ off) {
    int t = threadIdx.x;
    if (t < T_TYPES) {
        int run = 0;
        for (int c = 0; c < NBLK; ++c) { int v = bsum[t * NBLK + c]; bsum[t * NBLK + c] = run; run += v; }
        off[t * NOFF + N_NODES] = run;
    }
}

// Phase C: block-local exclusive scan + global offset -> off[] and cursor[]
// NOTE: counts/cursor may alias (in-place); each thread writes only what it read.
__global__ __launch_bounds__(256) void scan_c_kernel(const int* counts,
                                                     const int* __restrict__ bsum,
                                                     int* __restrict__ off,
                                                     int* cursor) {
    const int b = blockIdx.x;
    const int t = b / NBLK, ch = b % NBLK;
    const int tid = threadIdx.x, lane = tid & 63, w = tid >> 6;
    __shared__ int ws[4];
    const int* cnt = counts + t * N_NODES;
    int i0 = ch * 1024 + tid * 4;
    int v0 = 0, v1 = 0, v2 = 0, v3 = 0;
    if (i0 + 3 < N_NODES) { int4 v = *(const int4*)(cnt + i0); v0 = v.x; v1 = v.y; v2 = v.z; v3 = v.w; }
    else {
        if (i0     < N_NODES) v0 = cnt[i0];
        if (i0 + 1 < N_NODES) v1 = cnt[i0 + 1];
        if (i0 + 2 < N_NODES) v2 = cnt[i0 + 2];
        if (i0 + 3 < N_NODES) v3 = cnt[i0 + 3];
    }
    int s = v0 + v1 + v2 + v3;
    int x = s;
    #pragma unroll
    for (int o = 1; o < 64; o <<= 1) { int y = __shfl_up(x, o); if (lane >= o) x += y; }
    if (lane == 63) ws[w] = x;
    __syncthreads();
    int woff = 0;
    #pragma unroll
    for (int j = 0; j < 4; ++j) woff += (j < w) ? ws[j] : 0;
    int base = bsum[b] + woff + (x - s);
    int e0 = base, e1 = e0 + v0, e2 = e1 + v1, e3 = e2 + v2;
    if (i0 + 3 < N_NODES) {
        *(int4*)(off + t * NOFF + i0)       = make_int4(e0, e1, e2, e3);
        *(int4*)(cursor + t * N_NODES + i0) = make_int4(e0, e1, e2, e3);
    } else {
        if (i0     < N_NODES) { off[t * NOFF + i0]     = e0; cursor[t * N_NODES + i0]     = e0; }
        if (i0 + 1 < N_NODES) { off[t * NOFF + i0 + 1] = e1; cursor[t * N_NODES + i0 + 1] = e1; }
        if (i0 + 2 < N_NODES) { off[t * NOFF + i0 + 2] = e2; cursor[t * N_NODES + i0 + 2] = e2; }
        if (i0 + 3 < N_NODES) { off[t * NOFF + i0 + 3] = e3; cursor[t * N_NODES + i0 + 3] = e3; }
    }
}

__global__ void scatter_kernel(const int* __restrict__ esrc, const int* __restrict__ edst,
                               int* __restrict__ cursor, int* __restrict__ csrc,
                               const int* __restrict__ flag) {
    int idx = blockIdx.x * 256 + threadIdx.x;
    if (idx < T_TYPES * E_EDGES) {
        int sh = *flag;
        int t = idx / E_EDGES;
        int d = edst[(size_t)idx << sh];
        if ((unsigned)d >= N_NODES) return;
        int s = esrc[(size_t)idx << sh];
        if ((unsigned)s >= N_NODES) s = 0;
        int pos = atomicAdd(&cursor[t * N_NODES + d], 1);
        if ((unsigned)pos < E_EDGES)
            csrc[(size_t)t * E_EDGES + pos] = s;
    }
}

// ---------------- weight convert: Wt[lt][c(0..1023)][k] = bf16(W{l,r}[lt][k][c]) -----------
__global__ void wconv_kernel(const float* __restrict__ Wl, const float* __restrict__ Wr,
                             unsigned short* __restrict__ Wt) {
    int idx = blockIdx.x * 256 + threadIdx.x;
    if (idx >= L_LAYERS * T_TYPES * 1024 * H) return;
    int lt  = idx / (1024 * H);
    int rem = idx - lt * (1024 * H);
    int c   = rem / H;
    int k   = rem - c * H;
    float v = (c < HH) ? Wl[(size_t)lt * H * HH + (size_t)k * HH + c]
                       : Wr[(size_t)lt * H * HH + (size_t)k * HH + (c - HH)];
    Wt[idx] = f2bf(v);
}

// ---------------- init (fp32, round-3 proven): h = leaky(LN(feat@W+b)) ---------------------
// 8 nodes per 128-thread block
__global__ __launch_bounds__(128) void init_kernel(
    const float* __restrict__ feat, const float* __restrict__ emb,
    const float* __restrict__ W, const float* __restrict__ pb,
    const float* __restrict__ g, const float* __restrict__ b,
    float* __restrict__ x0, unsigned short* __restrict__ xcurb)
{
    __shared__ float lds[8][F_IN];
    __shared__ float s0[2], s1[2];
    const int tid = threadIdx.x;
    const int nb = blockIdx.x * 8;
    #pragma unroll
    for (int it = 0; it < 4; ++it) {
        int f = it * 512 + tid * 4;
        int r = f >> 8, c = f & 255;
        int node = nb + r;
        float4 v = make_float4(0.f, 0.f, 0.f, 0.f);
        if (node < N_NODES) v = *(const float4*)(feat + (size_t)node * F_IN + c);
        *(float4*)&lds[r][c] = v;
    }
    __syncthreads();
    const int c = tid;
    float acc[8];
    #pragma unroll
    for (int nn = 0; nn < 8; ++nn) acc[nn] = 0.f;
    for (int k = 0; k < F_IN; k += 4) {
        float w0 = W[(k + 0) * H + c];
        float w1 = W[(k + 1) * H + c];
        float w2 = W[(k + 2) * H + c];
        float w3 = W[(k + 3) * H + c];
        #pragma unroll
        for (int nn = 0; nn < 8; ++nn) {
            float4 xv = *(const float4*)&lds[nn][k];
            acc[nn] = fmaf(xv.x, w0, fmaf(xv.y, w1, fmaf(xv.z, w2, fmaf(xv.w, w3, acc[nn]))));
        }
    }
    const float pbc = pb[c], gc = g[c], bc = b[c];
    for (int nn = 0; nn < 8; ++nn) {
        float v = acc[nn] + pbc;
        float sum = v, sq = v * v;
        for (int o = 32; o > 0; o >>= 1) { sum += __shfl_down(sum, o); sq += __shfl_down(sq, o); }
        if ((tid & 63) == 0) { s0[tid >> 6] = sum; s1[tid >> 6] = sq; }
        __syncthreads();
        float tot = s0[0] + s0[1], tq = s1[0] + s1[1];
        __syncthreads();
        float mu = tot * (1.f / H);
        float var = tq * (1.f / H) - mu * mu;
        acc[nn] = leaky((v - mu) * rsqrtf(var + 1e-5f) * gc + bc);
    }
    for (int nn = 0; nn < 8; ++nn) {
        int node = nb + nn;
        float ev = (node < N_NODES) ? emb[(size_t)node * H + c] : 0.f;
        float sq = ev * ev;
        for (int o = 32; o > 0; o >>= 1) sq += __shfl_down(sq, o);
        if ((tid & 63) == 0) s0[tid >> 6] = sq;
        __syncthreads();
        float nrm = sqrtf(s0[0] + s0[1]);
        __syncthreads();
        float nev = ev / fmaxf(nrm, 1e-12f);
        float xv = 0.7f * acc[nn] + 0.5f * nev;
        if (node < N_NODES) {
            x0[(size_t)node * H + c] = xv;
            xcurb[(size_t)node * H + c] = f2bf(xv);
        }
    }
}

// ---------------- MFMA GEMM: [N,128]bf16 @ Wt^T -> XL|XR bf16, 128x128 tile ----------------
// blockIdx.x = column block (8): concurrent blocks share the x row-tile (L2/L3 friendly).
__global__ __launch_bounds__(256) void gemm_mfma_kernel(
    const unsigned short* __restrict__ x,    // [N][128] bf16
    const unsigned short* __restrict__ Wt,   // [1024][128] bf16 (this layer-type)
    unsigned short* __restrict__ XL, unsigned short* __restrict__ XR)
{
    __shared__ unsigned short smem[32768];   // 64 KB: As 32K | Bs 32K, then C overlay
    unsigned short* As = smem;
    unsigned short* Bs = smem + 16384;
    const int tid = threadIdx.x;
    const int nb = blockIdx.y * 128;
    const int cb = blockIdx.x * 128;

    #pragma unroll
    for (int it = 0; it < 8; ++it) {
        int c = it * 256 + tid;
        int r = c >> 4;
        int k8 = c & 15;
        int slot = (k8 ^ (r & 15)) * 8;
        int node = nb + r;
        uint4 va = make_uint4(0, 0, 0, 0);
        if (node < N_NODES) va = *(const uint4*)(x + (size_t)node * H + k8 * 8);
        *(uint4*)(As + r * H + slot) = va;
        uint4 vb = *(const uint4*)(Wt + (size_t)(cb + r) * H + k8 * 8);
        *(uint4*)(Bs + r * H + slot) = vb;
    }
    __syncthreads();

    const int wv = tid >> 6, lane = tid & 63;
    const int lm = lane & 15, kg = lane >> 4;
    const int wm = (wv & 1) * 64, wn = (wv >> 1) * 64;
    float4_t acc[4][4];
    #pragma unroll
    for (int i = 0; i < 4; ++i)
        #pragma unroll
        for (int j = 0; j < 4; ++j)
            acc[i][j] = (float4_t){0.f, 0.f, 0.f, 0.f};

    #pragma unroll
    for (int ks = 0; ks < 4; ++ks) {
        const int K8 = ks * 4 + kg;
        const int slot = (K8 ^ lm) * 8;
        short8_t a[4], b[4];
        #pragma unroll
        for (int i = 0; i < 4; ++i) {
            a[i] = *(const short8_t*)(As + (wm + i * 16 + lm) * H + slot);
            b[i] = *(const short8_t*)(Bs + (wn + i * 16 + lm) * H + slot);
        }
        #pragma unroll
        for (int i = 0; i < 4; ++i)
            #pragma unroll
            for (int j = 0; j < 4; ++j)
                acc[i][j] = __builtin_amdgcn_mfma_f32_16x16x32_bf16(a[i], b[j], acc[i][j], 0, 0, 0);
    }
    __syncthreads();

    unsigned short* Cs = smem;
    #pragma unroll
    for (int i = 0; i < 4; ++i) {
        int row0 = wm + i * 16 + kg * 4;
        #pragma unroll
        for (int j = 0; j < 4; ++j) {
            int col = wn + j * 16 + lm;
            #pragma unroll
            for (int r = 0; r < 4; ++r)
                Cs[(row0 + r) * 136 + col] = f2bf(acc[i][j][r]);
        }
    }
    __syncthreads();

    unsigned short* O = (blockIdx.x < 4) ? XL : XR;
    const int cbase = (blockIdx.x < 4) ? cb : cb - HH;
    #pragma unroll
    for (int it = 0; it < 8; ++it) {
        int c = it * 256 + tid;
        int r = c >> 4, k8 = (c & 15) * 8;
        int node = nb + r;
        if (node < N_NODES)
            *(uint4*)(O + (size_t)node * HH + cbase + k8) = *(const uint4*)(Cs + r * 136 + k8);
    }
}

// ---------------- per-dst flash-style GATv2 aggregation: 1 wave = 1 dst node ----------------
// Depth-2 software pipeline on the XL row gather (L3-latency-bound).
__global__ __launch_bounds__(256) void aggregate_kernel(
    const unsigned short* __restrict__ XL, const unsigned short* __restrict__ XR,
    const float* __restrict__ att_t, const float* __restrict__ bias_t,
    const int* __restrict__ off, const int* __restrict__ csrc,
    float* __restrict__ xacc, int first)
{
    const int tid = threadIdx.x;
    const int lane = tid & 63;
    const int wid = tid >> 6;
    const int d = blockIdx.x * 4 + wid;
    if (d >= N_NODES) return;
    const int jb = lane * 8;

    float rv[8], av[8], acc[8];
    {
        uint4 q = *(const uint4*)(XR + (size_t)d * HH + jb);
        unpack8(q, rv);
        float4 u0 = *(const float4*)(att_t + jb);
        float4 u1 = *(const float4*)(att_t + jb + 4);
        av[0] = u0.x; av[1] = u0.y; av[2] = u0.z; av[3] = u0.w;
        av[4] = u1.x; av[5] = u1.y; av[6] = u1.z; av[7] = u1.w;
    }
    #pragma unroll
    for (int u = 0; u < 8; ++u) acc[u] = 0.f;
    float den = 0.f, rmax = -INFINITY;

    const int e0 = off[d];
    const int cnt = off[d + 1] - e0;
    uint4 qA = make_uint4(0, 0, 0, 0), qB = qA;
    int sN = 0;
    if (cnt > 0) { unsigned s = csrc[e0];     if (s >= N_NODES) s = 0; qA = *(const uint4*)(XL + (size_t)s * HH + jb); }
    if (cnt > 1) { unsigned s = csrc[e0 + 1]; if (s >= N_NODES) s = 0; qB = *(const uint4*)(XL + (size_t)s * HH + jb); }
    if (cnt > 2) { unsigned s = csrc[e0 + 2]; if (s >= N_NODES) s = 0; sN = (int)s; }

    for (int e = 0; e < cnt; ++e) {
        float lv[8];
        unpack8(qA, lv);
        qA = qB;
        int sNN = 0;
        if (e + 3 < cnt) { unsigned s = csrc[e0 + e + 3]; if (s >= N_NODES) s = 0; sNN = (int)s; }
        if (e + 2 < cnt) qB = *(const uint4*)(XL + (size_t)sN * HH + jb);
        sN = sNN;
        float p = 0.f;
        #pragma unroll
        for (int u = 0; u < 8; ++u) {
            float m = lv[u] + rv[u];
            p = fmaf(av[u], leaky(m), p);
        }
        p += __shfl_xor(p, 1);
        p += __shfl_xor(p, 2);
        p += __shfl_xor(p, 4);
        p += __shfl_xor(p, 8);
        float nm = fmaxf(rmax, p);
        float sc = __expf(rmax - nm);
        float w  = __expf(p - nm);
        den = den * sc + w;
        #pragma unroll
        for (int u = 0; u < 8; ++u) acc[u] = fmaf(acc[u], sc, w * lv[u]);
        rmax = nm;
    }
    float inv = 1.f / (den + 1e-16f);
    #pragma unroll
    for (int u = 0; u < 8; ++u) {
        float v = acc[u] * inv;
        v += __shfl_xor(v, 16);
        v += __shfl_xor(v, 32);
        acc[u] = v * 0.25f;
    }
    if (lane < 16) {
        float* dst = xacc + (size_t)d * H + jb;
        float o[8];
        #pragma unroll
        for (int u = 0; u < 8; ++u) o[u] = acc[u] + bias_t[jb + u];
        float4 o0 = make_float4(o[0], o[1], o[2], o[3]);
        float4 o1 = make_float4(o[4], o[5], o[6], o[7]);
        if (first) {
            *(float4*)dst = o0;
            *(float4*)(dst + 4) = o1;
        } else {
            float4 c0 = *(const float4*)dst, c1 = *(const float4*)(dst + 4);
            o0.x += c0.x; o0.y += c0.y; o0.z += c0.z; o0.w += c0.w;
            o1.x += c1.x; o1.y += c1.y; o1.z += c1.z; o1.w += c1.w;
            *(float4*)dst = o0;
            *(float4*)(dst + 4) = o1;
        }
    }
}

// ---------------- layer epilogue ----------------
__global__ __launch_bounds__(256) void epilogue_kernel(
    const float* xacc, const float* __restrict__ x0,
    const float* __restrict__ skipw, int li, int last,
    unsigned short* __restrict__ xcurb, float* out)
{
    size_t i = ((size_t)blockIdx.x * 256 + threadIdx.x) * 4;
    float sw = 1.f / (1.f + __expf(-skipw[li]));
    float4 a = *(const float4*)(xacc + i);
    float4 z = *(const float4*)(x0 + i);
    float o0 = leaky(a.x * (1.f / 3.f)) + sw * z.x;
    float o1 = leaky(a.y * (1.f / 3.f)) + sw * z.y;
    float o2 = leaky(a.z * (1.f / 3.f)) + sw * z.z;
    float o3 = leaky(a.w * (1.f / 3.f)) + sw * z.w;
    if (last) {
        *(float4*)(out + i) = make_float4(o0, o1, o2, o3);
    } else {
        ushort4 o;
        o.x = f2bf(o0); o.y = f2bf(o1); o.z = f2bf(o2); o.w = f2bf(o3);
        *(ushort4*)(xcurb + i) = o;
    }
}

extern "C" void kernel_launch(void* const* d_in, const int* in_sizes, int n_in,
                              void* d_out, int out_size, void* d_ws, size_t ws_size,
                              hipStream_t stream)
{
    const float* feat   = (const float*)d_in[0];
    const float* emb    = (const float*)d_in[1];
    const float* proj_w = (const float*)d_in[2];
    const float* proj_b = (const float*)d_in[3];
    const float* ln_g   = (const float*)d_in[4];
    const float* ln_b   = (const float*)d_in[5];
    const float* skip_w = (const float*)d_in[6];
    const float* Wl     = (const float*)d_in[7];
    const float* Wr     = (const float*)d_in[8];
    const float* att    = (const float*)d_in[9];
    const float* bias   = (const float*)d_in[10];
    const int*   esrc   = (const int*)d_in[11];
    const int*   edst   = (const int*)d_in[12];
    float* out = (float*)d_out;

    char* p = (char*)d_ws;
    auto alloc = [&](size_t bytes) -> char* {
        char* r = p; p += (bytes + 255) & ~(size_t)255; return r;
    };
    float* x0             = (float*)alloc((size_t)N_NODES * H * 4);
    unsigned short* xcurb = (unsigned short*)alloc((size_t)N_NODES * H * 2);
    unsigned short* XL    = (unsigned short*)alloc((size_t)N_NODES * HH * 2);
    unsigned short* XR    = (unsigned short*)alloc((size_t)N_NODES * HH * 2);
    unsigned short* Wt    = (unsigned short*)alloc((size_t)L_LAYERS * T_TYPES * 1024 * H * 2);
    int* off    = (int*)alloc((size_t)T_TYPES * NOFF * 4);
    int* cursor = (int*)alloc((size_t)T_TYPES * N_NODES * 4);
    int* csrc   = (int*)alloc((size_t)T_TYPES * E_EDGES * 4);
    int* bsum   = (int*)alloc((size_t)T_TYPES * NBLK * 4);
    int* eflag  = (int*)alloc(256);
    float* xacc = out;  // alias scratch accumulator onto d_out

    detect_kernel<<<1, 256, 0, stream>>>(edst, eflag);
    hipMemsetAsync(cursor, 0, (size_t)T_TYPES * N_NODES * 4, stream);
    hist_kernel<<<(T_TYPES * E_EDGES + 255) / 256, 256, 0, stream>>>(edst, cursor, eflag);
    scan_a_kernel<<<T_TYPES * NBLK, 256, 0, stream>>>(cursor, bsum);
    scan_b_kernel<<<1, 256, 0, stream>>>(bsum, off);
    scan_c_kernel<<<T_TYPES * NBLK, 256, 0, stream>>>(cursor, bsum, off, cursor);
    scatter_kernel<<<(T_TYPES * E_EDGES + 255) / 256, 256, 0, stream>>>(esrc, edst, cursor, csrc, eflag);

    wconv_kernel<<<(L_LAYERS * T_TYPES * 1024 * H + 255) / 256, 256, 0, stream>>>(Wl, Wr, Wt);
    init_kernel<<<N_NODES / 8, 128, 0, stream>>>(feat, emb, proj_w, proj_b, ln_g, ln_b, x0, xcurb);

    for (int i = 0; i < L_LAYERS; ++i) {
        for (int t = 0; t < T_TYPES; ++t) {
            const int lt = i * T_TYPES + t;
            const unsigned short* wt = Wt + (size_t)lt * 1024 * H;
            const float* at = att + (size_t)lt * HEADS * H;
            const float* bi = bias + (size_t)lt * H;
            gemm_mfma_kernel<<<dim3(8, (N_NODES + 127) / 128), 256, 0, stream>>>(xcurb, wt, XL, XR);
            aggregate_kernel<<<(N_NODES + 3) / 4, 256, 0, stream>>>(
                XL, XR, at, bi, off + t * NOFF, csrc + (size_t)t * E_EDGES,
                xacc, (t == 0) ? 1 : 0);
        }
        epilogue_kernel<<<(N_NODES * H / 4) / 256, 256, 0, stream>>>(
            xacc, x0, skip_w, i, (i == L_LAYERS - 1) ? 1 : 0, xcurb, out);
    }
}

// Round 7
// 1199.019 us; speedup vs baseline: 2.4590x; 1.0231x over previous
//
#include <hip/hip_runtime.h>
#include <hip/hip_bf16.h>
#include <math.h>

#define N_NODES 50000
#define NOFF    50004   // padded off-array stride (16B-aligned int4 stores)
#define NBLK    49      // ceil(N_NODES/1024) scan blocks per type
#define F_IN    256
#define H       128
#define HEADS   4
#define HH      512   // HEADS*H
#define L_LAYERS 3
#define T_TYPES  3
#define E_EDGES  250000
#define NEG      0.2f

typedef __attribute__((ext_vector_type(8))) short short8_t;   // 8 bf16 (4 VGPRs)
typedef __attribute__((ext_vector_type(4))) float float4_t;

__device__ __forceinline__ float leaky(float x) { return x > 0.f ? x : NEG * x; }

__device__ __forceinline__ unsigned short f2bf(float f) {
    union { float f; unsigned int i; } v; v.f = f;
    unsigned int x = v.i;
    unsigned int r = (x + 0x7fffu + ((x >> 16) & 1u)) >> 16;  // RNE
    return (unsigned short)r;
}

__device__ __forceinline__ float bf2f(unsigned short u) {
    union { unsigned int i; float f; } v; v.i = ((unsigned)u) << 16; return v.f;
}

__device__ __forceinline__ void unpack8(uint4 q, float* o) {
    union { unsigned int i; float f; } v;
    v.i = q.x << 16;          o[0] = v.f;
    v.i = q.x & 0xffff0000u;  o[1] = v.f;
    v.i = q.y << 16;          o[2] = v.f;
    v.i = q.y & 0xffff0000u;  o[3] = v.f;
    v.i = q.z << 16;          o[4] = v.f;
    v.i = q.z & 0xffff0000u;  o[5] = v.f;
    v.i = q.w << 16;          o[6] = v.f;
    v.i = q.w & 0xffff0000u;  o[7] = v.f;
}

// ---------------- edge dtype detection: int64 vs int32 layout ----------------
__global__ void detect_kernel(const int* __restrict__ edst, int* __restrict__ flag) {
    __shared__ int s_any;
    if (threadIdx.x == 0) s_any = 0;
    __syncthreads();
    int a = 0;
    #pragma unroll
    for (int j = 0; j < 8; ++j) a |= edst[2 * (threadIdx.x * 8 + j) + 1];
    if (a) atomicOr(&s_any, 1);
    __syncthreads();
    if (threadIdx.x == 0) *flag = s_any ? 0 : 1;  // 1 => int64 layout (stride 2)
}

// ---------------- CSR build ----------------
__global__ void hist_kernel(const int* __restrict__ edst, int* __restrict__ counts,
                            const int* __restrict__ flag) {
    int idx = blockIdx.x * 256 + threadIdx.x;
    if (idx < T_TYPES * E_EDGES) {
        int sh = *flag;
        int t = idx / E_EDGES;
        int d = edst[(size_t)idx << sh];
        if ((unsigned)d < N_NODES)
            atomicAdd(&counts[t * N_NODES + d], 1);
    }
}

// Phase A: per-block partial sums (1024 counts/block, int4-coalesced)
__global__ __launch_bounds__(256) void scan_a_kernel(const int* __restrict__ counts,
                                                     int* __restrict__ bsum) {
    const int b = blockIdx.x;
    const int t = b / NBLK, ch = b % NBLK;
    const int tid = threadIdx.x, lane = tid & 63;
    __shared__ int ws[4];
    const int* cnt = counts + t * N_NODES;
    int i0 = ch * 1024 + tid * 4;
    int s = 0;
    if (i0 + 3 < N_NODES) { int4 v = *(const int4*)(cnt + i0); s = v.x + v.y + v.z + v.w; }
    else { for (int j = 0; j < 4; ++j) { int i = i0 + j; if (i < N_NODES) s += cnt[i]; } }
    #pragma unroll
    for (int o = 32; o > 0; o >>= 1) s += __shfl_xor(s, o);
    if (lane == 0) ws[tid >> 6] = s;
    __syncthreads();
    if (tid == 0) bsum[b] = ws[0] + ws[1] + ws[2] + ws[3];
}

// Phase B: exclusive-scan the 49 block sums per type (tiny, 1 block)
__global__ void scan_b_kernel(int* __restrict__ bsum, int* __restrict__ off) {
    int t = threadIdx.x;
    if (t < T_TYPES) {
        int run = 0;
        for (int c = 0; c < NBLK; ++c) { int v = bsum[t * NBLK + c]; bsum[t * NBLK + c] = run; run += v; }
        off[t * NOFF + N_NODES] = run;
    }
}

// Phase C: block-local exclusive scan + global offset -> off[] and cursor[]
__global__ __launch_bounds__(256) void scan_c_kernel(const int* counts,
                                                     const int* __restrict__ bsum,
                                                     int* __restrict__ off,
                                                     int* cursor) {
    const int b = blockIdx.x;
    const int t = b / NBLK, ch = b % NBLK;
    const int tid = threadIdx.x, lane = tid & 63, w = tid >> 6;
    __shared__ int ws[4];
    const int* cnt = counts + t * N_NODES;
    int i0 = ch * 1024 + tid * 4;
    int v0 = 0, v1 = 0, v2 = 0, v3 = 0;
    if (i0 + 3 < N_NODES) { int4 v = *(const int4*)(cnt + i0); v0 = v.x; v1 = v.y; v2 = v.z; v3 = v.w; }
    else {
        if (i0     < N_NODES) v0 = cnt[i0];
        if (i0 + 1 < N_NODES) v1 = cnt[i0 + 1];
        if (i0 + 2 < N_NODES) v2 = cnt[i0 + 2];
        if (i0 + 3 < N_NODES) v3 = cnt[i0 + 3];
    }
    int s = v0 + v1 + v2 + v3;
    int x = s;
    #pragma unroll
    for (int o = 1; o < 64; o <<= 1) { int y = __shfl_up(x, o); if (lane >= o) x += y; }
    if (lane == 63) ws[w] = x;
    __syncthreads();
    int woff = 0;
    #pragma unroll
    for (int j = 0; j < 4; ++j) woff += (j < w) ? ws[j] : 0;
    int base = bsum[b] + woff + (x - s);
    int e0 = base, e1 = e0 + v0, e2 = e1 + v1, e3 = e2 + v2;
    if (i0 + 3 < N_NODES) {
        *(int4*)(off + t * NOFF + i0)       = make_int4(e0, e1, e2, e3);
        *(int4*)(cursor + t * N_NODES + i0) = make_int4(e0, e1, e2, e3);
    } else {
        if (i0     < N_NODES) { off[t * NOFF + i0]     = e0; cursor[t * N_NODES + i0]     = e0; }
        if (i0 + 1 < N_NODES) { off[t * NOFF + i0 + 1] = e1; cursor[t * N_NODES + i0 + 1] = e1; }
        if (i0 + 2 < N_NODES) { off[t * NOFF + i0 + 2] = e2; cursor[t * N_NODES + i0 + 2] = e2; }
        if (i0 + 3 < N_NODES) { off[t * NOFF + i0 + 3] = e3; cursor[t * N_NODES + i0 + 3] = e3; }
    }
}

__global__ void scatter_kernel(const int* __restrict__ esrc, const int* __restrict__ edst,
                               int* __restrict__ cursor, int* __restrict__ csrc,
                               const int* __restrict__ flag) {
    int idx = blockIdx.x * 256 + threadIdx.x;
    if (idx < T_TYPES * E_EDGES) {
        int sh = *flag;
        int t = idx / E_EDGES;
        int d = edst[(size_t)idx << sh];
        if ((unsigned)d >= N_NODES) return;
        int s = esrc[(size_t)idx << sh];
        if ((unsigned)s >= N_NODES) s = 0;
        int pos = atomicAdd(&cursor[t * N_NODES + d], 1);
        if ((unsigned)pos < E_EDGES)
            csrc[(size_t)t * E_EDGES + pos] = s;
    }
}

// ---------------- weight convert: Wt[lt][c(0..1023)][k] = bf16(W{l,r}[lt][k][c]) -----------
__global__ void wconv_kernel(const float* __restrict__ Wl, const float* __restrict__ Wr,
                             unsigned short* __restrict__ Wt) {
    int idx = blockIdx.x * 256 + threadIdx.x;
    if (idx >= L_LAYERS * T_TYPES * 1024 * H) return;
    int lt  = idx / (1024 * H);
    int rem = idx - lt * (1024 * H);
    int c   = rem / H;
    int k   = rem - c * H;
    float v = (c < HH) ? Wl[(size_t)lt * H * HH + (size_t)k * HH + c]
                       : Wr[(size_t)lt * H * HH + (size_t)k * HH + (c - HH)];
    Wt[idx] = f2bf(v);
}

// feat fp32 [N,256] -> split bf16 fHi/fLo [N,256]
__global__ void featconv_kernel(const float* __restrict__ feat,
                                unsigned short* __restrict__ fHi,
                                unsigned short* __restrict__ fLo) {
    size_t i = ((size_t)blockIdx.x * 256 + threadIdx.x) * 4;
    if (i >= (size_t)N_NODES * F_IN) return;
    float4 v = *(const float4*)(feat + i);
    ushort4 h, l;
    h.x = f2bf(v.x); l.x = f2bf(v.x - bf2f(h.x));
    h.y = f2bf(v.y); l.y = f2bf(v.y - bf2f(h.y));
    h.z = f2bf(v.z); l.z = f2bf(v.z - bf2f(h.z));
    h.w = f2bf(v.w); l.w = f2bf(v.w - bf2f(h.w));
    *(ushort4*)(fHi + i) = h;
    *(ushort4*)(fLo + i) = l;
}

// proj_w [256,128] fp32 -> pWtHi/pWtLo [128 cols][256 k] split-bf16
__global__ void pconv_kernel(const float* __restrict__ pw,
                             unsigned short* __restrict__ pWtHi,
                             unsigned short* __restrict__ pWtLo) {
    int idx = blockIdx.x * 256 + threadIdx.x;
    if (idx >= H * F_IN) return;
    int c = idx / F_IN, k = idx - c * F_IN;
    float v = pw[(size_t)k * H + c];
    unsigned short hi = f2bf(v);
    pWtHi[idx] = hi;
    pWtLo[idx] = f2bf(v - bf2f(hi));
}

// stage a 128x128 bf16 tile (16B chunks, XOR swizzle) -- identical pattern to gemm_mfma
__device__ __forceinline__ void stage_tile(unsigned short* dst, const unsigned short* src,
                                           int rbase, int kbase, int tid, bool guardRows) {
    #pragma unroll
    for (int it = 0; it < 8; ++it) {
        int c = it * 256 + tid;          // 0..2047
        int r = c >> 4, k8 = c & 15;
        int slot = (k8 ^ (r & 15)) * 8;
        uint4 v = make_uint4(0, 0, 0, 0);
        int row = rbase + r;
        if (!guardRows || row < N_NODES)
            v = *(const uint4*)(src + (size_t)row * 256 + kbase + k8 * 8);
        *(uint4*)(dst + r * 128 + slot) = v;
    }
}

// ---------------- init GEMM (split-bf16 MFMA, proven gemm structure): proj = feat@W fp32 ----
// 128x128 tile, K=256 in two 128-chunks, 3 hi/lo passes each: hi*hi + lo*hi + hi*lo.
__global__ __launch_bounds__(256) void init_gemm_kernel(
    const unsigned short* __restrict__ fHi, const unsigned short* __restrict__ fLo,
    const unsigned short* __restrict__ pWtHi, const unsigned short* __restrict__ pWtLo,
    float* __restrict__ proj)
{
    __shared__ unsigned short smem[32768];   // As 32K | Bs 32K
    unsigned short* As = smem;
    unsigned short* Bs = smem + 16384;
    const int tid = threadIdx.x;
    const int nb = blockIdx.x * 128;

    const int wv = tid >> 6, lane = tid & 63;
    const int lm = lane & 15, kg = lane >> 4;
    const int wm = (wv & 1) * 64, wn = (wv >> 1) * 64;
    float4_t acc[4][4];
    #pragma unroll
    for (int i = 0; i < 4; ++i)
        #pragma unroll
        for (int j = 0; j < 4; ++j)
            acc[i][j] = (float4_t){0.f, 0.f, 0.f, 0.f};

    auto compute = [&]() {
        #pragma unroll
        for (int ks = 0; ks < 4; ++ks) {
            const int K8 = ks * 4 + kg;
            const int slot = (K8 ^ lm) * 8;
            short8_t a[4], b[4];
            #pragma unroll
            for (int i = 0; i < 4; ++i) {
                a[i] = *(const short8_t*)(As + (wm + i * 16 + lm) * 128 + slot);
                b[i] = *(const short8_t*)(Bs + (wn + i * 16 + lm) * 128 + slot);
            }
            #pragma unroll
            for (int i = 0; i < 4; ++i)
                #pragma unroll
                for (int j = 0; j < 4; ++j)
                    acc[i][j] = __builtin_amdgcn_mfma_f32_16x16x32_bf16(a[i], b[j], acc[i][j], 0, 0, 0);
        }
    };

    #pragma unroll
    for (int kh = 0; kh < 2; ++kh) {
        const int kbase = kh * 128;
        // (hi, hi)
        stage_tile(As, fHi, nb, kbase, tid, true);
        stage_tile(Bs, pWtHi, 0, kbase, tid, false);
        __syncthreads();
        compute();
        __syncthreads();
        // (hi, lo): restage B only
        stage_tile(Bs, pWtLo, 0, kbase, tid, false);
        __syncthreads();
        compute();
        __syncthreads();
        // (lo, hi)
        stage_tile(As, fLo, nb, kbase, tid, true);
        stage_tile(Bs, pWtHi, 0, kbase, tid, false);
        __syncthreads();
        compute();
        __syncthreads();
    }

    // direct fp32 stores in C/D layout (col=lane&15, row=kg*4+reg)
    #pragma unroll
    for (int i = 0; i < 4; ++i) {
        #pragma unroll
        for (int r = 0; r < 4; ++r) {
            int node = nb + wm + i * 16 + kg * 4 + r;
            if (node < N_NODES) {
                #pragma unroll
                for (int j = 0; j < 4; ++j)
                    proj[(size_t)node * H + wn + j * 16 + lm] = acc[i][j][r];
            }
        }
    }
}

// ---------------- LN + combine (round-3 proven numerics): x0 = 0.7*leaky(LN(proj+b)) + 0.5*l2n(emb)
__global__ __launch_bounds__(128) void ln_combine_kernel(
    const float* __restrict__ proj, const float* __restrict__ emb,
    const float* __restrict__ pb, const float* __restrict__ g, const float* __restrict__ b,
    float* __restrict__ x0, unsigned short* __restrict__ xcurb)
{
    __shared__ float s0[2], s1[2];
    const int tid = threadIdx.x;
    const int nb = blockIdx.x * 8;
    const int c = tid;
    float acc[8];
    #pragma unroll
    for (int nn = 0; nn < 8; ++nn) {
        int node = nb + nn;
        acc[nn] = (node < N_NODES) ? proj[(size_t)node * H + c] : 0.f;
    }
    const float pbc = pb[c], gc = g[c], bc = b[c];
    for (int nn = 0; nn < 8; ++nn) {
        float v = acc[nn] + pbc;
        float sum = v, sq = v * v;
        for (int o = 32; o > 0; o >>= 1) { sum += __shfl_down(sum, o); sq += __shfl_down(sq, o); }
        if ((tid & 63) == 0) { s0[tid >> 6] = sum; s1[tid >> 6] = sq; }
        __syncthreads();
        float tot = s0[0] + s0[1], tq = s1[0] + s1[1];
        __syncthreads();
        float mu = tot * (1.f / H);
        float var = tq * (1.f / H) - mu * mu;
        acc[nn] = leaky((v - mu) * rsqrtf(var + 1e-5f) * gc + bc);
    }
    for (int nn = 0; nn < 8; ++nn) {
        int node = nb + nn;
        float ev = (node < N_NODES) ? emb[(size_t)node * H + c] : 0.f;
        float sq = ev * ev;
        for (int o = 32; o > 0; o >>= 1) sq += __shfl_down(sq, o);
        if ((tid & 63) == 0) s0[tid >> 6] = sq;
        __syncthreads();
        float nrm = sqrtf(s0[0] + s0[1]);
        __syncthreads();
        float nev = ev / fmaxf(nrm, 1e-12f);
        float xv = 0.7f * acc[nn] + 0.5f * nev;
        if (node < N_NODES) {
            x0[(size_t)node * H + c] = xv;
            xcurb[(size_t)node * H + c] = f2bf(xv);
        }
    }
}

// ---------------- MFMA GEMM: [N,128]bf16 @ Wt^T -> XL|XR bf16, 128x128 tile ----------------
__global__ __launch_bounds__(256) void gemm_mfma_kernel(
    const unsigned short* __restrict__ x,    // [N][128] bf16
    const unsigned short* __restrict__ Wt,   // [1024][128] bf16 (this layer-type)
    unsigned short* __restrict__ XL, unsigned short* __restrict__ XR)
{
    __shared__ unsigned short smem[32768];   // 64 KB: As 32K | Bs 32K, then C overlay
    unsigned short* As = smem;
    unsigned short* Bs = smem + 16384;
    const int tid = threadIdx.x;
    const int nb = blockIdx.y * 128;
    const int cb = blockIdx.x * 128;

    #pragma unroll
    for (int it = 0; it < 8; ++it) {
        int c = it * 256 + tid;
        int r = c >> 4;
        int k8 = c & 15;
        int slot = (k8 ^ (r & 15)) * 8;
        int node = nb + r;
        uint4 va = make_uint4(0, 0, 0, 0);
        if (node < N_NODES) va = *(const uint4*)(x + (size_t)node * H + k8 * 8);
        *(uint4*)(As + r * H + slot) = va;
        uint4 vb = *(const uint4*)(Wt + (size_t)(cb + r) * H + k8 * 8);
        *(uint4*)(Bs + r * H + slot) = vb;
    }
    __syncthreads();

    const int wv = tid >> 6, lane = tid & 63;
    const int lm = lane & 15, kg = lane >> 4;
    const int wm = (wv & 1) * 64, wn = (wv >> 1) * 64;
    float4_t acc[4][4];
    #pragma unroll
    for (int i = 0; i < 4; ++i)
        #pragma unroll
        for (int j = 0; j < 4; ++j)
            acc[i][j] = (float4_t){0.f, 0.f, 0.f, 0.f};

    #pragma unroll
    for (int ks = 0; ks < 4; ++ks) {
        const int K8 = ks * 4 + kg;
        const int slot = (K8 ^ lm) * 8;
        short8_t a[4], b[4];
        #pragma unroll
        for (int i = 0; i < 4; ++i) {
            a[i] = *(const short8_t*)(As + (wm + i * 16 + lm) * H + slot);
            b[i] = *(const short8_t*)(Bs + (wn + i * 16 + lm) * H + slot);
        }
        #pragma unroll
        for (int i = 0; i < 4; ++i)
            #pragma unroll
            for (int j = 0; j < 4; ++j)
                acc[i][j] = __builtin_amdgcn_mfma_f32_16x16x32_bf16(a[i], b[j], acc[i][j], 0, 0, 0);
    }
    __syncthreads();

    unsigned short* Cs = smem;
    #pragma unroll
    for (int i = 0; i < 4; ++i) {
        int row0 = wm + i * 16 + kg * 4;
        #pragma unroll
        for (int j = 0; j < 4; ++j) {
            int col = wn + j * 16 + lm;
            #pragma unroll
            for (int r = 0; r < 4; ++r)
                Cs[(row0 + r) * 136 + col] = f2bf(acc[i][j][r]);
        }
    }
    __syncthreads();

    unsigned short* O = (blockIdx.x < 4) ? XL : XR;
    const int cbase = (blockIdx.x < 4) ? cb : cb - HH;
    #pragma unroll
    for (int it = 0; it < 8; ++it) {
        int c = it * 256 + tid;
        int r = c >> 4, k8 = (c & 15) * 8;
        int node = nb + r;
        if (node < N_NODES)
            *(uint4*)(O + (size_t)node * HH + cbase + k8) = *(const uint4*)(Cs + r * 136 + k8);
    }
}

// ---------------- per-dst flash-style GATv2 aggregation: 1 wave = 1 dst node ----------------
__global__ __launch_bounds__(256) void aggregate_kernel(
    const unsigned short* __restrict__ XL, const unsigned short* __restrict__ XR,
    const float* __restrict__ att_t, const float* __restrict__ bias_t,
    const int* __restrict__ off, const int* __restrict__ csrc,
    float* __restrict__ xacc, int first)
{
    const int tid = threadIdx.x;
    const int lane = tid & 63;
    const int wid = tid >> 6;
    const int d = blockIdx.x * 4 + wid;
    if (d >= N_NODES) return;
    const int jb = lane * 8;

    float rv[8], av[8], acc[8];
    {
        uint4 q = *(const uint4*)(XR + (size_t)d * HH + jb);
        unpack8(q, rv);
        float4 u0 = *(const float4*)(att_t + jb);
        float4 u1 = *(const float4*)(att_t + jb + 4);
        av[0] = u0.x; av[1] = u0.y; av[2] = u0.z; av[3] = u0.w;
        av[4] = u1.x; av[5] = u1.y; av[6] = u1.z; av[7] = u1.w;
    }
    #pragma unroll
    for (int u = 0; u < 8; ++u) acc[u] = 0.f;
    float den = 0.f, rmax = -INFINITY;

    const int e0 = off[d];
    const int cnt = off[d + 1] - e0;
    uint4 qA = make_uint4(0, 0, 0, 0), qB = qA;
    int sN = 0;
    if (cnt > 0) { unsigned s = csrc[e0];     if (s >= N_NODES) s = 0; qA = *(const uint4*)(XL + (size_t)s * HH + jb); }
    if (cnt > 1) { unsigned s = csrc[e0 + 1]; if (s >= N_NODES) s = 0; qB = *(const uint4*)(XL + (size_t)s * HH + jb); }
    if (cnt > 2) { unsigned s = csrc[e0 + 2]; if (s >= N_NODES) s = 0; sN = (int)s; }

    for (int e = 0; e < cnt; ++e) {
        float lv[8];
        unpack8(qA, lv);
        qA = qB;
        int sNN = 0;
        if (e + 3 < cnt) { unsigned s = csrc[e0 + e + 3]; if (s >= N_NODES) s = 0; sNN = (int)s; }
        if (e + 2 < cnt) qB = *(const uint4*)(XL + (size_t)sN * HH + jb);
        sN = sNN;
        float p = 0.f;
        #pragma unroll
        for (int u = 0; u < 8; ++u) {
            float m = lv[u] + rv[u];
            p = fmaf(av[u], leaky(m), p);
        }
        p += __shfl_xor(p, 1);
        p += __shfl_xor(p, 2);
        p += __shfl_xor(p, 4);
        p += __shfl_xor(p, 8);
        float nm = fmaxf(rmax, p);
        float sc = __expf(rmax - nm);
        float w  = __expf(p - nm);
        den = den * sc + w;
        #pragma unroll
        for (int u = 0; u < 8; ++u) acc[u] = fmaf(acc[u], sc, w * lv[u]);
        rmax = nm;
    }
    float inv = 1.f / (den + 1e-16f);
    #pragma unroll
    for (int u = 0; u < 8; ++u) {
        float v = acc[u] * inv;
        v += __shfl_xor(v, 16);
        v += __shfl_xor(v, 32);
        acc[u] = v * 0.25f;
    }
    if (lane < 16) {
        float* dst = xacc + (size_t)d * H + jb;
        float o[8];
        #pragma unroll
        for (int u = 0; u < 8; ++u) o[u] = acc[u] + bias_t[jb + u];
        float4 o0 = make_float4(o[0], o[1], o[2], o[3]);
        float4 o1 = make_float4(o[4], o[5], o[6], o[7]);
        if (first) {
            *(float4*)dst = o0;
            *(float4*)(dst + 4) = o1;
        } else {
            float4 c0 = *(const float4*)dst, c1 = *(const float4*)(dst + 4);
            o0.x += c0.x; o0.y += c0.y; o0.z += c0.z; o0.w += c0.w;
            o1.x += c1.x; o1.y += c1.y; o1.z += c1.z; o1.w += c1.w;
            *(float4*)dst = o0;
            *(float4*)(dst + 4) = o1;
        }
    }
}

// ---------------- layer epilogue ----------------
__global__ __launch_bounds__(256) void epilogue_kernel(
    const float* xacc, const float* __restrict__ x0,
    const float* __restrict__ skipw, int li, int last,
    unsigned short* __restrict__ xcurb, float* out)
{
    size_t i = ((size_t)blockIdx.x * 256 + threadIdx.x) * 4;
    float sw = 1.f / (1.f + __expf(-skipw[li]));
    float4 a = *(const float4*)(xacc + i);
    float4 z = *(const float4*)(x0 + i);
    float o0 = leaky(a.x * (1.f / 3.f)) + sw * z.x;
    float o1 = leaky(a.y * (1.f / 3.f)) + sw * z.y;
    float o2 = leaky(a.z * (1.f / 3.f)) + sw * z.z;
    float o3 = leaky(a.w * (1.f / 3.f)) + sw * z.w;
    if (last) {
        *(float4*)(out + i) = make_float4(o0, o1, o2, o3);
    } else {
        ushort4 o;
        o.x = f2bf(o0); o.y = f2bf(o1); o.z = f2bf(o2); o.w = f2bf(o3);
        *(ushort4*)(xcurb + i) = o;
    }
}

extern "C" void kernel_launch(void* const* d_in, const int* in_sizes, int n_in,
                              void* d_out, int out_size, void* d_ws, size_t ws_size,
                              hipStream_t stream)
{
    const float* feat   = (const float*)d_in[0];
    const float* emb    = (const float*)d_in[1];
    const float* proj_w = (const float*)d_in[2];
    const float* proj_b = (const float*)d_in[3];
    const float* ln_g   = (const float*)d_in[4];
    const float* ln_b   = (const float*)d_in[5];
    const float* skip_w = (const float*)d_in[6];
    const float* Wl     = (const float*)d_in[7];
    const float* Wr     = (const float*)d_in[8];
    const float* att    = (const float*)d_in[9];
    const float* bias   = (const float*)d_in[10];
    const int*   esrc   = (const int*)d_in[11];
    const int*   edst   = (const int*)d_in[12];
    float* out = (float*)d_out;

    char* p = (char*)d_ws;
    auto alloc = [&](size_t bytes) -> char* {
        char* r = p; p += (bytes + 255) & ~(size_t)255; return r;
    };
    float* x0             = (float*)alloc((size_t)N_NODES * H * 4);
    unsigned short* xcurb = (unsigned short*)alloc((size_t)N_NODES * H * 2);
    unsigned short* XL    = (unsigned short*)alloc((size_t)N_NODES * HH * 2);
    unsigned short* XR    = (unsigned short*)alloc((size_t)N_NODES * HH * 2);
    unsigned short* Wt    = (unsigned short*)alloc((size_t)L_LAYERS * T_TYPES * 1024 * H * 2);
    unsigned short* pWtHi = (unsigned short*)alloc((size_t)H * F_IN * 2);
    unsigned short* pWtLo = (unsigned short*)alloc((size_t)H * F_IN * 2);
    int* off    = (int*)alloc((size_t)T_TYPES * NOFF * 4);
    int* cursor = (int*)alloc((size_t)T_TYPES * N_NODES * 4);
    int* csrc   = (int*)alloc((size_t)T_TYPES * E_EDGES * 4);
    int* bsum   = (int*)alloc((size_t)T_TYPES * NBLK * 4);
    int* eflag  = (int*)alloc(256);
    float* xacc = out;  // alias scratch accumulator onto d_out

    // init-phase scratch aliases the (still-dead) XL/XR regions: zero extra ws
    float* proj          = (float*)XL;                                   // 25.6 MB <= 51.2
    unsigned short* fHi  = XR;                                           // 25.6 MB
    unsigned short* fLo  = XR + (size_t)N_NODES * F_IN;                  // 25.6 MB (= 51.2 total)

    detect_kernel<<<1, 256, 0, stream>>>(edst, eflag);
    hipMemsetAsync(cursor, 0, (size_t)T_TYPES * N_NODES * 4, stream);
    hist_kernel<<<(T_TYPES * E_EDGES + 255) / 256, 256, 0, stream>>>(edst, cursor, eflag);
    scan_a_kernel<<<T_TYPES * NBLK, 256, 0, stream>>>(cursor, bsum);
    scan_b_kernel<<<1, 256, 0, stream>>>(bsum, off);
    scan_c_kernel<<<T_TYPES * NBLK, 256, 0, stream>>>(cursor, bsum, off, cursor);
    scatter_kernel<<<(T_TYPES * E_EDGES + 255) / 256, 256, 0, stream>>>(esrc, edst, cursor, csrc, eflag);

    wconv_kernel<<<(L_LAYERS * T_TYPES * 1024 * H + 255) / 256, 256, 0, stream>>>(Wl, Wr, Wt);
    featconv_kernel<<<((N_NODES * F_IN / 4) + 255) / 256, 256, 0, stream>>>(feat, fHi, fLo);
    pconv_kernel<<<(H * F_IN + 255) / 256, 256, 0, stream>>>(proj_w, pWtHi, pWtLo);
    init_gemm_kernel<<<(N_NODES + 127) / 128, 256, 0, stream>>>(fHi, fLo, pWtHi, pWtLo, proj);
    ln_combine_kernel<<<N_NODES / 8, 128, 0, stream>>>(proj, emb, proj_b, ln_g, ln_b, x0, xcurb);

    for (int i = 0; i < L_LAYERS; ++i) {
        for (int t = 0; t < T_TYPES; ++t) {
            const int lt = i * T_TYPES + t;
            const unsigned short* wt = Wt + (size_t)lt * 1024 * H;
            const float* at = att + (size_t)lt * HEADS * H;
            const float* bi = bias + (size_t)lt * H;
            gemm_mfma_kernel<<<dim3(8, (N_NODES + 127) / 128), 256, 0, stream>>>(xcurb, wt, XL, XR);
            aggregate_kernel<<<(N_NODES + 3) / 4, 256, 0, stream>>>(
                XL, XR, at, bi, off + t * NOFF, csrc + (size_t)t * E_EDGES,
                xacc, (t == 0) ? 1 : 0);
        }
        epilogue_kernel<<<(N_NODES * H / 4) / 256, 256, 0, stream>>>(
            xacc, x0, skip_w, i, (i == L_LAYERS - 1) ? 1 : 0, xcurb, out);
    }
}